// Round 1
// baseline (567.347 us; speedup 1.0000x reference)
//
#include <hip/hip_runtime.h>
#include <hip/hip_bf16.h>
#include <math.h>

#define IN_DIM 256
#define D1 256      // HEADS*HID = 4*64
#define C2 32       // conv2 out channels
#define NEG 0.2f

// ---------------- utility kernels ----------------
__global__ void zero_i32(int* __restrict__ p, int n) {
    int i = blockIdx.x * blockDim.x + threadIdx.x;
    if (i < n) p[i] = 0;
}

// histogram of destination degrees (edges + self loops)
__global__ void hist_kernel(const int* __restrict__ ei, int E, int N, int* __restrict__ cnt) {
    int i = blockIdx.x * blockDim.x + threadIdx.x;
    int tot = E + N;
    if (i >= tot) return;
    int d = (i < E) ? ei[E + i] : (i - E);
    atomicAdd(&cnt[d], 1);
}

// single-block exclusive scan over N entries -> row_ptr[0..N], cursor copy
__global__ void scan_kernel(const int* __restrict__ cnt, int* __restrict__ row_ptr,
                            int* __restrict__ cursor, int N) {
    __shared__ int sdata[1024];
    __shared__ int srun;
    if (threadIdx.x == 0) srun = 0;
    __syncthreads();
    int nch = (N + 1023) >> 10;
    for (int ch = 0; ch < nch; ++ch) {
        int i = (ch << 10) + threadIdx.x;
        int val = (i < N) ? cnt[i] : 0;
        sdata[threadIdx.x] = val;
        __syncthreads();
        for (int off = 1; off < 1024; off <<= 1) {
            int t = (threadIdx.x >= off) ? sdata[threadIdx.x - off] : 0;
            __syncthreads();
            sdata[threadIdx.x] += t;
            __syncthreads();
        }
        int base = srun;
        if (i < N) {
            int rp = base + sdata[threadIdx.x] - val;  // exclusive
            row_ptr[i] = rp;
            cursor[i] = rp;
        }
        __syncthreads();
        if (threadIdx.x == 1023) srun = base + sdata[1023];
        __syncthreads();
    }
    if (threadIdx.x == 0) row_ptr[N] = srun;
}

__global__ void scatter_kernel(const int* __restrict__ ei, int E, int N,
                               int* __restrict__ cursor, int* __restrict__ col) {
    int i = blockIdx.x * blockDim.x + threadIdx.x;
    int tot = E + N;
    if (i >= tot) return;
    int s, d;
    if (i < E) { s = ei[i]; d = ei[E + i]; }
    else       { s = i - E; d = s; }
    int pos = atomicAdd(&cursor[d], 1);
    col[pos] = s;
}

// ---------------- GEMM1: h1[M,256] = x[M,256] @ W1[256,256] (fp32) ----------------
__global__ __launch_bounds__(256) void gemm1_kernel(const float* __restrict__ A,
                                                    const float* __restrict__ B,
                                                    float* __restrict__ C, int M) {
    __shared__ float As[64][17];
    __shared__ float Bs[16][68];
    int t = threadIdx.x;
    int tx = t & 15, ty = t >> 4;
    int row0 = blockIdx.x * 64;
    int col0 = blockIdx.y * 64;
    float acc[4][4] = {};
    for (int k0 = 0; k0 < 256; k0 += 16) {
        int ar = t >> 2, ak = (t & 3) << 2;
        int grow = row0 + ar;
        float4 av = {0.f, 0.f, 0.f, 0.f};
        if (grow < M) av = *reinterpret_cast<const float4*>(A + (size_t)grow * 256 + k0 + ak);
        As[ar][ak + 0] = av.x; As[ar][ak + 1] = av.y; As[ar][ak + 2] = av.z; As[ar][ak + 3] = av.w;
        int bk = t >> 4, bn = (t & 15) << 2;
        float4 bv = *reinterpret_cast<const float4*>(B + (size_t)(k0 + bk) * 256 + col0 + bn);
        Bs[bk][bn + 0] = bv.x; Bs[bk][bn + 1] = bv.y; Bs[bk][bn + 2] = bv.z; Bs[bk][bn + 3] = bv.w;
        __syncthreads();
#pragma unroll
        for (int kk = 0; kk < 16; ++kk) {
            float a0 = As[ty * 4 + 0][kk];
            float a1 = As[ty * 4 + 1][kk];
            float a2 = As[ty * 4 + 2][kk];
            float a3 = As[ty * 4 + 3][kk];
            float b0 = Bs[kk][tx * 4 + 0];
            float b1 = Bs[kk][tx * 4 + 1];
            float b2 = Bs[kk][tx * 4 + 2];
            float b3 = Bs[kk][tx * 4 + 3];
            acc[0][0] += a0 * b0; acc[0][1] += a0 * b1; acc[0][2] += a0 * b2; acc[0][3] += a0 * b3;
            acc[1][0] += a1 * b0; acc[1][1] += a1 * b1; acc[1][2] += a1 * b2; acc[1][3] += a1 * b3;
            acc[2][0] += a2 * b0; acc[2][1] += a2 * b1; acc[2][2] += a2 * b2; acc[2][3] += a2 * b3;
            acc[3][0] += a3 * b0; acc[3][1] += a3 * b1; acc[3][2] += a3 * b2; acc[3][3] += a3 * b3;
        }
        __syncthreads();
    }
#pragma unroll
    for (int i = 0; i < 4; ++i) {
        int grow = row0 + ty * 4 + i;
        if (grow < M) {
            float4 o = {acc[i][0], acc[i][1], acc[i][2], acc[i][3]};
            *reinterpret_cast<float4*>(C + (size_t)grow * 256 + col0 + tx * 4) = o;
        }
    }
}

// ---------------- attention logits conv1: one 64-lane wave per node ----------------
__global__ void att1_kernel(const float* __restrict__ h1, const float* __restrict__ att_s,
                            const float* __restrict__ att_d, float* __restrict__ as1,
                            float* __restrict__ ad1, int N) {
    int idx = blockIdx.x * blockDim.x + threadIdx.x;
    int v = idx >> 6, lane = idx & 63;
    if (v >= N) return;
    float4 hv = *reinterpret_cast<const float4*>(h1 + (size_t)v * 256 + lane * 4);
    float4 s4 = *reinterpret_cast<const float4*>(att_s + lane * 4);
    float4 d4 = *reinterpret_cast<const float4*>(att_d + lane * 4);
    float ps = hv.x * s4.x + hv.y * s4.y + hv.z * s4.z + hv.w * s4.w;
    float pd = hv.x * d4.x + hv.y * d4.y + hv.z * d4.z + hv.w * d4.w;
#pragma unroll
    for (int off = 1; off < 16; off <<= 1) {
        ps += __shfl_xor(ps, off, 64);
        pd += __shfl_xor(pd, off, 64);
    }
    if ((lane & 15) == 0) {
        as1[v * 4 + (lane >> 4)] = ps;
        ad1[v * 4 + (lane >> 4)] = pd;
    }
}

// ---------------- conv1 aggregation: one wave per node, online softmax ----------------
__global__ void conv1_agg(const float* __restrict__ h1, const float* __restrict__ as1,
                          const float* __restrict__ ad1, const int* __restrict__ row_ptr,
                          const int* __restrict__ col, const float* __restrict__ b1,
                          float* __restrict__ hin2, int N) {
    int idx = blockIdx.x * blockDim.x + threadIdx.x;
    int v = idx >> 6, lane = idx & 63;
    if (v >= N) return;
    int head = lane >> 4;
    float adst = ad1[v * 4 + head];
    int beg = row_ptr[v], end = row_ptr[v + 1];
    float m = -1e30f, l = 0.f;
    float ax = 0.f, ay = 0.f, az = 0.f, aw = 0.f;
    for (int p = beg; p < end; ++p) {
        int u = col[p];
        float e = as1[u * 4 + head] + adst;
        e = e > 0.f ? e : NEG * e;
        float m2 = fmaxf(m, e);
        float s = __expf(m - m2);
        float pw = __expf(e - m2);
        l = l * s + pw;
        const float4 hv = *reinterpret_cast<const float4*>(h1 + (size_t)u * 256 + lane * 4);
        ax = ax * s + pw * hv.x;
        ay = ay * s + pw * hv.y;
        az = az * s + pw * hv.z;
        aw = aw * s + pw * hv.w;
        m = m2;
    }
    float inv = 1.f / (l + 1e-16f);
    int c = lane * 4;
    float4 o;
    o.x = fmaxf(ax * inv + b1[c + 0], 0.f);
    o.y = fmaxf(ay * inv + b1[c + 1], 0.f);
    o.z = fmaxf(az * inv + b1[c + 2], 0.f);
    o.w = fmaxf(aw * inv + b1[c + 3], 0.f);
    *reinterpret_cast<float4*>(hin2 + (size_t)v * 256 + c) = o;
}

// ---------------- GEMM2 (256->32) + att2 epilogue ----------------
__global__ __launch_bounds__(256) void gemm2_att(const float* __restrict__ hin2,
                                                 const float* __restrict__ W2,
                                                 const float* __restrict__ att_s,
                                                 const float* __restrict__ att_d,
                                                 float* __restrict__ h2, float* __restrict__ as2,
                                                 float* __restrict__ ad2, int N) {
    __shared__ float w[256 * 32];
    int t = threadIdx.x;
#pragma unroll
    for (int i = 0; i < 8; ++i) {
        int idx = (i * 256 + t) * 4;
        float4 wv = *reinterpret_cast<const float4*>(W2 + idx);
        w[idx + 0] = wv.x; w[idx + 1] = wv.y; w[idx + 2] = wv.z; w[idx + 3] = wv.w;
    }
    __syncthreads();
    int n = blockIdx.x * 8 + (t >> 5);
    int j = t & 31;
    if (n >= N) return;
    float acc = 0.f;
    for (int k0 = 0; k0 < 256; k0 += 4) {
        float4 hv = *reinterpret_cast<const float4*>(hin2 + (size_t)n * 256 + k0);
        acc += hv.x * w[(k0 + 0) * 32 + j];
        acc += hv.y * w[(k0 + 1) * 32 + j];
        acc += hv.z * w[(k0 + 2) * 32 + j];
        acc += hv.w * w[(k0 + 3) * 32 + j];
    }
    h2[(size_t)n * 32 + j] = acc;
    float vs = acc * att_s[j];
    float vd = acc * att_d[j];
#pragma unroll
    for (int off = 1; off < 32; off <<= 1) {
        vs += __shfl_xor(vs, off, 64);
        vd += __shfl_xor(vd, off, 64);
    }
    if (j == 0) { as2[n] = vs; ad2[n] = vd; }
}

// ---------------- conv2 aggregation: 32 lanes per node ----------------
__global__ void conv2_agg(const float* __restrict__ h2, const float* __restrict__ as2,
                          const float* __restrict__ ad2, const int* __restrict__ row_ptr,
                          const int* __restrict__ col, const float* __restrict__ b2,
                          float* __restrict__ out2, int N) {
    int idx = blockIdx.x * blockDim.x + threadIdx.x;
    int v = idx >> 5, lane = idx & 31;
    if (v >= N) return;
    float adst = ad2[v];
    int beg = row_ptr[v], end = row_ptr[v + 1];
    float m = -1e30f, l = 0.f, acc = 0.f;
    for (int p = beg; p < end; ++p) {
        int u = col[p];
        float e = as2[u] + adst;
        e = e > 0.f ? e : NEG * e;
        float m2 = fmaxf(m, e);
        float s = __expf(m - m2);
        float pw = __expf(e - m2);
        l = l * s + pw;
        acc = acc * s + pw * h2[(size_t)u * 32 + lane];
        m = m2;
    }
    out2[(size_t)v * 32 + lane] = acc / (l + 1e-16f) + b2[lane];
}

// ---------------- pooling + FC head: one block per graph ----------------
__global__ __launch_bounds__(256) void pool_fc(const float* __restrict__ out2,
                                               const int* __restrict__ batch,
                                               const float* __restrict__ fc1w,
                                               const float* __restrict__ fc1b,
                                               const float* __restrict__ fc2w,
                                               const float* __restrict__ fc2b,
                                               float* __restrict__ out, int N) {
    int g = blockIdx.x;
    // lower_bound(g) / lower_bound(g+1) on sorted batch
    int lo = 0, hi = N;
    while (lo < hi) { int mid = (lo + hi) >> 1; if (batch[mid] < g) lo = mid + 1; else hi = mid; }
    int s = lo;
    lo = 0; hi = N;
    while (lo < hi) { int mid = (lo + hi) >> 1; if (batch[mid] < g + 1) lo = mid + 1; else hi = mid; }
    int e = lo;

    int c = threadIdx.x & 31, grp = threadIdx.x >> 5;  // 8 row-groups
    float sum = 0.f;
    for (int r = s + grp; r < e; r += 8) sum += out2[(size_t)r * 32 + c];
    __shared__ float part[8][32];
    part[grp][c] = sum;
    __syncthreads();
    __shared__ float g0[32];
    if (grp == 0) {
        float tot = 0.f;
#pragma unroll
        for (int q = 0; q < 8; ++q) tot += part[q][c];
        float cnt = (float)(e - s);
        float gv = tot / fmaxf(cnt, 1.0f);
        g0[c] = fmaxf(gv, 0.f);
    }
    __syncthreads();
    __shared__ float z1[16];
    if (threadIdx.x < 16) {
        float a = fc1b[threadIdx.x];
        for (int k = 0; k < 32; ++k) a += g0[k] * fc1w[k * 16 + threadIdx.x];
        z1[threadIdx.x] = fmaxf(a, 0.f);
    }
    __syncthreads();
    if (threadIdx.x < 16) {
        float a = fc2b[threadIdx.x];
        for (int k = 0; k < 16; ++k) a += z1[k] * fc2w[k * 16 + threadIdx.x];
        out[g * 16 + threadIdx.x] = fmaxf(a, 0.f);
    }
}

// ---------------- host launcher ----------------
extern "C" void kernel_launch(void* const* d_in, const int* in_sizes, int n_in,
                              void* d_out, int out_size, void* d_ws, size_t ws_size,
                              hipStream_t stream) {
    const float* x      = (const float*)d_in[0];
    const int*   ei     = (const int*)d_in[1];
    const int*   batch  = (const int*)d_in[2];
    const float* W1     = (const float*)d_in[3];
    const float* att_s1 = (const float*)d_in[4];
    const float* att_d1 = (const float*)d_in[5];
    const float* b1     = (const float*)d_in[6];
    const float* W2     = (const float*)d_in[7];
    const float* att_s2 = (const float*)d_in[8];
    const float* att_d2 = (const float*)d_in[9];
    const float* b2     = (const float*)d_in[10];
    const float* fc1w   = (const float*)d_in[11];
    const float* fc1b   = (const float*)d_in[12];
    const float* fc2w   = (const float*)d_in[13];
    const float* fc2b   = (const float*)d_in[14];
    float* out = (float*)d_out;

    int N = in_sizes[0] / IN_DIM;   // 50000
    int E = in_sizes[1] / 2;        // 800000
    int ET = E + N;

    char* ws = (char*)d_ws;
    size_t off = 0;
    auto alloc = [&](size_t bytes) { size_t o = off; off = (off + bytes + 255) & ~255ULL; return o; };
    float* h1     = (float*)(ws + alloc((size_t)N * D1 * 4));
    float* hin2   = (float*)(ws + alloc((size_t)N * D1 * 4));
    float* as1    = (float*)(ws + alloc((size_t)N * 4 * 4));
    float* ad1    = (float*)(ws + alloc((size_t)N * 4 * 4));
    float* h2     = (float*)(ws + alloc((size_t)N * C2 * 4));
    float* as2    = (float*)(ws + alloc((size_t)N * 4));
    float* ad2    = (float*)(ws + alloc((size_t)N * 4));
    float* out2   = (float*)(ws + alloc((size_t)N * C2 * 4));
    int* cnt      = (int*)(ws + alloc((size_t)(N + 1) * 4));
    int* row_ptr  = (int*)(ws + alloc((size_t)(N + 1) * 4));
    int* cursor   = (int*)(ws + alloc((size_t)(N + 1) * 4));
    int* col      = (int*)(ws + alloc((size_t)ET * 4));
    (void)ws_size; (void)n_in; (void)out_size;

    // CSR build
    zero_i32<<<(N + 1 + 255) / 256, 256, 0, stream>>>(cnt, N + 1);
    hist_kernel<<<(ET + 255) / 256, 256, 0, stream>>>(ei, E, N, cnt);
    scan_kernel<<<1, 1024, 0, stream>>>(cnt, row_ptr, cursor, N);
    scatter_kernel<<<(ET + 255) / 256, 256, 0, stream>>>(ei, E, N, cursor, col);

    // conv1
    dim3 g1((N + 63) / 64, 4);
    gemm1_kernel<<<g1, 256, 0, stream>>>(x, W1, h1, N);
    att1_kernel<<<(N * 64 + 255) / 256, 256, 0, stream>>>(h1, att_s1, att_d1, as1, ad1, N);
    conv1_agg<<<(N * 64 + 255) / 256, 256, 0, stream>>>(h1, as1, ad1, row_ptr, col, b1, hin2, N);

    // conv2
    gemm2_att<<<(N + 7) / 8, 256, 0, stream>>>(hin2, W2, att_s2, att_d2, h2, as2, ad2, N);
    conv2_agg<<<(N * 32 + 255) / 256, 256, 0, stream>>>(h2, as2, ad2, row_ptr, col, b2, out2, N);

    // pool + fc
    pool_fc<<<64, 256, 0, stream>>>(out2, batch, fc1w, fc1b, fc2w, fc2b, out, N);
}

// Round 2
// 384.617 us; speedup vs baseline: 1.4751x; 1.4751x over previous
//
#include <hip/hip_runtime.h>
#include <math.h>

#define NEG 0.2f
typedef unsigned short u16;
typedef __bf16 bf16x8 __attribute__((ext_vector_type(8)));
typedef float f32x4 __attribute__((ext_vector_type(4)));

__device__ __forceinline__ float bf2f(u16 u) {
    union { unsigned i; float f; } x; x.i = ((unsigned)u) << 16; return x.f;
}
__device__ __forceinline__ u16 f2bf(float f) {
    union { float f; unsigned u; } x; x.f = f;
    unsigned r = x.u + 0x7fffu + ((x.u >> 16) & 1u);
    return (u16)(r >> 16);
}

// ---------------- utility ----------------
__global__ void zero_i32(int* __restrict__ p, int n) {
    int i = blockIdx.x * blockDim.x + threadIdx.x;
    if (i < n) p[i] = 0;
}

__global__ void hist_kernel(const int* __restrict__ ei, int E, int N, int* __restrict__ cnt) {
    int i = blockIdx.x * blockDim.x + threadIdx.x;
    int tot = E + N;
    if (i >= tot) return;
    int d = (i < E) ? ei[E + i] : (i - E);
    atomicAdd(&cnt[d], 1);
}

__global__ void bsum_kernel(const int* __restrict__ cnt, int* __restrict__ bsum, int N) {
    __shared__ int sd[256];
    int i = blockIdx.x * 256 + threadIdx.x;
    sd[threadIdx.x] = (i < N) ? cnt[i] : 0;
    __syncthreads();
    for (int off = 128; off; off >>= 1) {
        if (threadIdx.x < off) sd[threadIdx.x] += sd[threadIdx.x + off];
        __syncthreads();
    }
    if (threadIdx.x == 0) bsum[blockIdx.x] = sd[0];
}

__global__ void bscan_kernel(const int* __restrict__ bsum, int* __restrict__ bbase, int NB) {
    __shared__ int sd[256];
    int t = threadIdx.x;
    int v = (t < NB) ? bsum[t] : 0;
    sd[t] = v;
    __syncthreads();
    for (int off = 1; off < 256; off <<= 1) {
        int u = (t >= off) ? sd[t - off] : 0;
        __syncthreads();
        sd[t] += u;
        __syncthreads();
    }
    if (t < NB) bbase[t] = sd[t] - v;
}

__global__ void local_scan_kernel(const int* __restrict__ cnt, const int* __restrict__ bbase,
                                  int* __restrict__ row_ptr, int* __restrict__ cursor,
                                  int N, int ET) {
    __shared__ int sd[256];
    int t = threadIdx.x;
    int i = blockIdx.x * 256 + t;
    int v = (i < N) ? cnt[i] : 0;
    sd[t] = v;
    __syncthreads();
    for (int off = 1; off < 256; off <<= 1) {
        int u = (t >= off) ? sd[t - off] : 0;
        __syncthreads();
        sd[t] += u;
        __syncthreads();
    }
    if (i < N) {
        int e = bbase[blockIdx.x] + sd[t] - v;
        row_ptr[i] = e;
        cursor[i] = e;
    }
    if (i == 0) row_ptr[N] = ET;
}

__global__ void scatter_kernel(const int* __restrict__ ei, int E, int N,
                               int* __restrict__ cursor, int* __restrict__ col) {
    int i = blockIdx.x * blockDim.x + threadIdx.x;
    int tot = E + N;
    if (i >= tot) return;
    int s, d;
    if (i < E) { s = ei[i]; d = ei[E + i]; }
    else       { s = i - E; d = s; }
    int pos = atomicAdd(&cursor[d], 1);
    col[pos] = s;
}

// ---------------- casts ----------------
// x [Nreal][256] fp32 -> xb [Mpad][256] bf16 (pad rows zero). 8 elems/thread.
__global__ void cast_x_kernel(const float* __restrict__ x, u16* __restrict__ xb,
                              int Nreal, int Mpad) {
    int i = blockIdx.x * blockDim.x + threadIdx.x;
    size_t base = (size_t)i * 8;
    if (base >= (size_t)Mpad * 256) return;
    int row = (int)(base >> 8);
    uint4 o;
    if (row < Nreal) {
        float4 a = *reinterpret_cast<const float4*>(x + base);
        float4 b = *reinterpret_cast<const float4*>(x + base + 4);
        o.x = (unsigned)f2bf(a.x) | ((unsigned)f2bf(a.y) << 16);
        o.y = (unsigned)f2bf(a.z) | ((unsigned)f2bf(a.w) << 16);
        o.z = (unsigned)f2bf(b.x) | ((unsigned)f2bf(b.y) << 16);
        o.w = (unsigned)f2bf(b.z) | ((unsigned)f2bf(b.w) << 16);
    } else {
        o = make_uint4(0, 0, 0, 0);
    }
    *reinterpret_cast<uint4*>(xb + base) = o;
}

// W1 [256][256] -> W1T bf16 [256][256]  (W1T[c][k] = W1[k][c])
__global__ void cast_w1t_kernel(const float* __restrict__ W1, u16* __restrict__ W1T) {
    int k = blockIdx.x, c = threadIdx.x;
    W1T[c * 256 + k] = f2bf(W1[k * 256 + c]);
}

// ---------------- GEMM1 MFMA: h1[Mpad,256] = xb @ W1T^T, fused att epilogue --------
// block 256 thr = 4 waves (2x2), tile 128x128, BK=64 (4 steps), XOR-swizzled LDS
__global__ __launch_bounds__(256) void gemm1_mfma(const u16* __restrict__ Ab,
                                                  const u16* __restrict__ Bt,
                                                  const float* __restrict__ att_s,
                                                  const float* __restrict__ att_d,
                                                  u16* __restrict__ h1b,
                                                  float* __restrict__ as1,
                                                  float* __restrict__ ad1,
                                                  int Nnodes) {
    __shared__ __align__(16) u16 As[128 * 64];
    __shared__ __align__(16) u16 Bs[128 * 64];
    int t = threadIdx.x;
    int lane = t & 63, wave = t >> 6;
    int wm = wave >> 1, wn = wave & 1;
    int r0 = blockIdx.x * 128, c0 = blockIdx.y * 128;

    // staging: chunk id c = i*256 + t ; row = c>>3, j = c&7 (8 x 16B blocks per 64-elem row)
    int srow_base = t >> 3;   // + i*32
    int sj = t & 7;

    f32x4 acc[4][4];
#pragma unroll
    for (int m = 0; m < 4; ++m)
#pragma unroll
        for (int n = 0; n < 4; ++n) acc[m][n] = (f32x4){0.f, 0.f, 0.f, 0.f};

    uint4 ra[4], rb[4];
    // prologue load k0=0
#pragma unroll
    for (int i = 0; i < 4; ++i) {
        int row = i * 32 + srow_base;
        ra[i] = *reinterpret_cast<const uint4*>(Ab + (size_t)(r0 + row) * 256 + sj * 8);
        rb[i] = *reinterpret_cast<const uint4*>(Bt + (size_t)(c0 + row) * 256 + sj * 8);
    }

    char* As8 = (char*)As;
    char* Bs8 = (char*)Bs;

    for (int s = 0; s < 4; ++s) {
        __syncthreads();
#pragma unroll
        for (int i = 0; i < 4; ++i) {
            int row = i * 32 + srow_base;
            int dst = row * 128 + ((sj ^ (row & 7)) << 4);
            *reinterpret_cast<uint4*>(As8 + dst) = ra[i];
            *reinterpret_cast<uint4*>(Bs8 + dst) = rb[i];
        }
        __syncthreads();
        if (s < 3) {
            int k0 = (s + 1) * 64;
#pragma unroll
            for (int i = 0; i < 4; ++i) {
                int row = i * 32 + srow_base;
                ra[i] = *reinterpret_cast<const uint4*>(Ab + (size_t)(r0 + row) * 256 + k0 + sj * 8);
                rb[i] = *reinterpret_cast<const uint4*>(Bt + (size_t)(c0 + row) * 256 + k0 + sj * 8);
            }
        }
#pragma unroll
        for (int ks = 0; ks < 2; ++ks) {
            bf16x8 af[4], bf[4];
            int g = lane >> 4;
            int l15 = lane & 15;
#pragma unroll
            for (int m = 0; m < 4; ++m) {
                int arow = wm * 64 + m * 16 + l15;
                int ajb = (ks * 4 + g) ^ (arow & 7);
                af[m] = *reinterpret_cast<const bf16x8*>(As8 + arow * 128 + ajb * 16);
            }
#pragma unroll
            for (int n = 0; n < 4; ++n) {
                int brow = wn * 64 + n * 16 + l15;
                int bjb = (ks * 4 + g) ^ (brow & 7);
                bf[n] = *reinterpret_cast<const bf16x8*>(Bs8 + brow * 128 + bjb * 16);
            }
#pragma unroll
            for (int m = 0; m < 4; ++m)
#pragma unroll
                for (int n = 0; n < 4; ++n)
                    acc[m][n] = __builtin_amdgcn_mfma_f32_16x16x32_bf16(af[m], bf[n], acc[m][n], 0, 0, 0);
        }
    }

    // epilogue: write bf16 h1, compute per-head att dots
    int l15 = lane & 15;
    int g = lane >> 4;
    int head = blockIdx.y * 2 + wn;
    float asv[4], adv[4];
#pragma unroll
    for (int n = 0; n < 4; ++n) {
        asv[n] = att_s[head * 64 + n * 16 + l15];
        adv[n] = att_d[head * 64 + n * 16 + l15];
    }
#pragma unroll
    for (int m = 0; m < 4; ++m) {
#pragma unroll
        for (int reg = 0; reg < 4; ++reg) {
            int grow = r0 + wm * 64 + m * 16 + g * 4 + reg;
            bool ok = grow < Nnodes;
            float vs = 0.f, vd = 0.f;
#pragma unroll
            for (int n = 0; n < 4; ++n) {
                float v = acc[m][n][reg];
                if (ok) h1b[(size_t)grow * 256 + c0 + wn * 64 + n * 16 + l15] = f2bf(v);
                vs += v * asv[n];
                vd += v * adv[n];
            }
#pragma unroll
            for (int mask = 1; mask < 16; mask <<= 1) {
                vs += __shfl_xor(vs, mask, 64);
                vd += __shfl_xor(vd, mask, 64);
            }
            if (l15 == 0 && ok) {
                as1[grow * 4 + head] = vs;
                ad1[grow * 4 + head] = vd;
            }
        }
    }
}

// ---------------- conv1 aggregation (bf16 gather, online softmax) ----------------
__global__ void conv1_agg(const u16* __restrict__ h1b, const float* __restrict__ as1,
                          const float* __restrict__ ad1, const int* __restrict__ row_ptr,
                          const int* __restrict__ col, const float* __restrict__ b1,
                          u16* __restrict__ hin2b, int N) {
    int idx = blockIdx.x * blockDim.x + threadIdx.x;
    int v = idx >> 6, lane = idx & 63;
    if (v >= N) return;
    int head = lane >> 4;
    float adst = ad1[v * 4 + head];
    int beg = row_ptr[v], end = row_ptr[v + 1];
    float m = -1e30f, l = 0.f;
    float ax = 0.f, ay = 0.f, az = 0.f, aw = 0.f;
    for (int p = beg; p < end; ++p) {
        int u = col[p];
        float e = as1[u * 4 + head] + adst;
        e = e > 0.f ? e : NEG * e;
        float m2 = fmaxf(m, e);
        float sc = __expf(m - m2);
        float pw = __expf(e - m2);
        l = l * sc + pw;
        ushort4 hv = *reinterpret_cast<const ushort4*>(h1b + (size_t)u * 256 + lane * 4);
        ax = ax * sc + pw * bf2f(hv.x);
        ay = ay * sc + pw * bf2f(hv.y);
        az = az * sc + pw * bf2f(hv.z);
        aw = aw * sc + pw * bf2f(hv.w);
        m = m2;
    }
    float inv = 1.f / (l + 1e-16f);
    int c = lane * 4;
    ushort4 o;
    o.x = f2bf(fmaxf(ax * inv + b1[c + 0], 0.f));
    o.y = f2bf(fmaxf(ay * inv + b1[c + 1], 0.f));
    o.z = f2bf(fmaxf(az * inv + b1[c + 2], 0.f));
    o.w = f2bf(fmaxf(aw * inv + b1[c + 3], 0.f));
    *reinterpret_cast<ushort4*>(hin2b + (size_t)v * 256 + c) = o;
}

// ---------------- GEMM2 (256->32) fp32 weights, bf16 activations, fused att2 -------
// block 256 = 4 waves; per wave 8 nodes (two 32-lane halves x 4 nodes); W2T in LDS [32][268]
__global__ __launch_bounds__(256) void gemm2_att(const u16* __restrict__ hin2b,
                                                 const float* __restrict__ W2,
                                                 const float* __restrict__ att_s,
                                                 const float* __restrict__ att_d,
                                                 u16* __restrict__ h2b, float* __restrict__ as2,
                                                 float* __restrict__ ad2, int N) {
    __shared__ __align__(16) float ws2[32 * 268];
    int t = threadIdx.x;
#pragma unroll
    for (int i = 0; i < 32; ++i) {
        int flat = i * 256 + t;
        int j2 = flat & 31, k2 = flat >> 5;
        ws2[j2 * 268 + k2] = W2[flat];
    }
    __syncthreads();
    int wave = t >> 6, half = (t >> 5) & 1, j = t & 31;
    int nb = blockIdx.x * 32 + wave * 8 + half * 4;
    float acc[4] = {0.f, 0.f, 0.f, 0.f};
    int nmax = N - 1;
    for (int k0 = 0; k0 < 256; k0 += 4) {
        float4 w4 = *reinterpret_cast<const float4*>(ws2 + j * 268 + k0);
#pragma unroll
        for (int q = 0; q < 4; ++q) {
            int nc = nb + q; nc = nc > nmax ? nmax : nc;
            ushort4 h = *reinterpret_cast<const ushort4*>(hin2b + (size_t)nc * 256 + k0);
            acc[q] += bf2f(h.x) * w4.x + bf2f(h.y) * w4.y + bf2f(h.z) * w4.z + bf2f(h.w) * w4.w;
        }
    }
    float asj = att_s[j], adj = att_d[j];
#pragma unroll
    for (int q = 0; q < 4; ++q) {
        int n = nb + q;
        bool ok = n < N;
        float a = acc[q];
        if (ok) h2b[(size_t)n * 32 + j] = f2bf(a);
        float vs = a * asj, vd = a * adj;
#pragma unroll
        for (int mask = 1; mask < 32; mask <<= 1) {
            vs += __shfl_xor(vs, mask, 64);
            vd += __shfl_xor(vd, mask, 64);
        }
        if (j == 0 && ok) { as2[n] = vs; ad2[n] = vd; }
    }
}

// ---------------- conv2 aggregation (bf16 gather) ----------------
__global__ void conv2_agg(const u16* __restrict__ h2b, const float* __restrict__ as2,
                          const float* __restrict__ ad2, const int* __restrict__ row_ptr,
                          const int* __restrict__ col, const float* __restrict__ b2,
                          float* __restrict__ out2, int N) {
    int idx = blockIdx.x * blockDim.x + threadIdx.x;
    int v = idx >> 5, lane = idx & 31;
    if (v >= N) return;
    float adst = ad2[v];
    int beg = row_ptr[v], end = row_ptr[v + 1];
    float m = -1e30f, l = 0.f, acc = 0.f;
    for (int p = beg; p < end; ++p) {
        int u = col[p];
        float e = as2[u] + adst;
        e = e > 0.f ? e : NEG * e;
        float m2 = fmaxf(m, e);
        float sc = __expf(m - m2);
        float pw = __expf(e - m2);
        l = l * sc + pw;
        acc = acc * sc + pw * bf2f(h2b[(size_t)u * 32 + lane]);
        m = m2;
    }
    out2[(size_t)v * 32 + lane] = acc / (l + 1e-16f) + b2[lane];
}

// ---------------- pooling + FC head ----------------
__global__ __launch_bounds__(256) void pool_fc(const float* __restrict__ out2,
                                               const int* __restrict__ batch,
                                               const float* __restrict__ fc1w,
                                               const float* __restrict__ fc1b,
                                               const float* __restrict__ fc2w,
                                               const float* __restrict__ fc2b,
                                               float* __restrict__ out, int N) {
    int g = blockIdx.x;
    int lo = 0, hi = N;
    while (lo < hi) { int mid = (lo + hi) >> 1; if (batch[mid] < g) lo = mid + 1; else hi = mid; }
    int s = lo;
    lo = 0; hi = N;
    while (lo < hi) { int mid = (lo + hi) >> 1; if (batch[mid] < g + 1) lo = mid + 1; else hi = mid; }
    int e = lo;

    int c = threadIdx.x & 31, grp = threadIdx.x >> 5;
    float sum = 0.f;
    for (int r = s + grp; r < e; r += 8) sum += out2[(size_t)r * 32 + c];
    __shared__ float part[8][32];
    part[grp][c] = sum;
    __syncthreads();
    __shared__ float g0[32];
    if (grp == 0) {
        float tot = 0.f;
#pragma unroll
        for (int q = 0; q < 8; ++q) tot += part[q][c];
        float cnt = (float)(e - s);
        g0[c] = fmaxf(tot / fmaxf(cnt, 1.0f), 0.f);
    }
    __syncthreads();
    __shared__ float z1[16];
    if (threadIdx.x < 16) {
        float a = fc1b[threadIdx.x];
        for (int k = 0; k < 32; ++k) a += g0[k] * fc1w[k * 16 + threadIdx.x];
        z1[threadIdx.x] = fmaxf(a, 0.f);
    }
    __syncthreads();
    if (threadIdx.x < 16) {
        float a = fc2b[threadIdx.x];
        for (int k = 0; k < 16; ++k) a += z1[k] * fc2w[k * 16 + threadIdx.x];
        out[g * 16 + threadIdx.x] = fmaxf(a, 0.f);
    }
}

// ---------------- host launcher ----------------
extern "C" void kernel_launch(void* const* d_in, const int* in_sizes, int n_in,
                              void* d_out, int out_size, void* d_ws, size_t ws_size,
                              hipStream_t stream) {
    const float* x      = (const float*)d_in[0];
    const int*   ei     = (const int*)d_in[1];
    const int*   batch  = (const int*)d_in[2];
    const float* W1     = (const float*)d_in[3];
    const float* att_s1 = (const float*)d_in[4];
    const float* att_d1 = (const float*)d_in[5];
    const float* b1     = (const float*)d_in[6];
    const float* W2     = (const float*)d_in[7];
    const float* att_s2 = (const float*)d_in[8];
    const float* att_d2 = (const float*)d_in[9];
    const float* b2     = (const float*)d_in[10];
    const float* fc1w   = (const float*)d_in[11];
    const float* fc1b   = (const float*)d_in[12];
    const float* fc2w   = (const float*)d_in[13];
    const float* fc2b   = (const float*)d_in[14];
    float* out = (float*)d_out;

    int N = in_sizes[0] / 256;      // 50000
    int E = in_sizes[1] / 2;        // 800000
    int ET = E + N;
    int Mpad = ((N + 127) / 128) * 128;
    int NB = (N + 255) / 256;

    char* ws = (char*)d_ws;
    size_t off = 0;
    auto alloc = [&](size_t bytes) { size_t o = off; off = (off + bytes + 255) & ~255ULL; return o; };
    u16*  xb     = (u16*)(ws + alloc((size_t)Mpad * 256 * 2));
    u16*  w1t    = (u16*)(ws + alloc(256 * 256 * 2));
    u16*  h1b    = (u16*)(ws + alloc((size_t)N * 256 * 2));
    float* as1   = (float*)(ws + alloc((size_t)N * 4 * 4));
    float* ad1   = (float*)(ws + alloc((size_t)N * 4 * 4));
    u16*  hin2b  = (u16*)(ws + alloc((size_t)N * 256 * 2));
    u16*  h2b    = (u16*)(ws + alloc((size_t)N * 32 * 2));
    float* as2   = (float*)(ws + alloc((size_t)N * 4));
    float* ad2   = (float*)(ws + alloc((size_t)N * 4));
    float* out2  = (float*)(ws + alloc((size_t)N * 32 * 4));
    int* cnt     = (int*)(ws + alloc((size_t)(N + 1) * 4));
    int* row_ptr = (int*)(ws + alloc((size_t)(N + 1) * 4));
    int* cursor  = (int*)(ws + alloc((size_t)(N + 1) * 4));
    int* col     = (int*)(ws + alloc((size_t)ET * 4));
    int* bsum    = (int*)(ws + alloc((size_t)NB * 4));
    int* bbase   = (int*)(ws + alloc((size_t)NB * 4));
    (void)ws_size; (void)n_in; (void)out_size;

    // casts (independent of CSR)
    cast_x_kernel<<<Mpad / 8, 256, 0, stream>>>(x, xb, N, Mpad);
    cast_w1t_kernel<<<256, 256, 0, stream>>>(W1, w1t);

    // CSR build
    zero_i32<<<(N + 1 + 255) / 256, 256, 0, stream>>>(cnt, N + 1);
    hist_kernel<<<(ET + 255) / 256, 256, 0, stream>>>(ei, E, N, cnt);
    bsum_kernel<<<NB, 256, 0, stream>>>(cnt, bsum, N);
    bscan_kernel<<<1, 256, 0, stream>>>(bsum, bbase, NB);
    local_scan_kernel<<<NB, 256, 0, stream>>>(cnt, bbase, row_ptr, cursor, N, ET);
    scatter_kernel<<<(ET + 255) / 256, 256, 0, stream>>>(ei, E, N, cursor, col);

    // conv1
    dim3 g1(Mpad / 128, 2);
    gemm1_mfma<<<g1, 256, 0, stream>>>(xb, w1t, att_s1, att_d1, h1b, as1, ad1, N);
    conv1_agg<<<(N * 64 + 255) / 256, 256, 0, stream>>>(h1b, as1, ad1, row_ptr, col, b1, hin2b, N);

    // conv2
    gemm2_att<<<(N + 31) / 32, 256, 0, stream>>>(hin2b, W2, att_s2, att_d2, h2b, as2, ad2, N);
    conv2_agg<<<(N * 32 + 255) / 256, 256, 0, stream>>>(h2b, as2, ad2, row_ptr, col, b2, out2, N);

    // pool + fc
    pool_fc<<<64, 256, 0, stream>>>(out2, batch, fc1w, fc1b, fc2w, fc2b, out, N);
}

// Round 3
// 349.531 us; speedup vs baseline: 1.6232x; 1.1004x over previous
//
#include <hip/hip_runtime.h>
#include <math.h>

#define NEG 0.2f
typedef unsigned short u16;
typedef __bf16 bf16x8 __attribute__((ext_vector_type(8)));
typedef float f32x4 __attribute__((ext_vector_type(4)));

__device__ __forceinline__ float bf2f(u16 u) {
    union { unsigned i; float f; } x; x.i = ((unsigned)u) << 16; return x.f;
}
__device__ __forceinline__ u16 f2bf(float f) {
    union { float f; unsigned u; } x; x.f = f;
    unsigned r = x.u + 0x7fffu + ((x.u >> 16) & 1u);
    return (u16)(r >> 16);
}

// ---------------- utility ----------------
__global__ void zero_i32(int* __restrict__ p, int n) {
    int i = blockIdx.x * blockDim.x + threadIdx.x;
    if (i < n) p[i] = 0;
}

__global__ void hist_kernel(const int* __restrict__ ei, int E, int N, int* __restrict__ cnt) {
    int i = blockIdx.x * blockDim.x + threadIdx.x;
    int tot = E + N;
    if (i >= tot) return;
    int d = (i < E) ? ei[E + i] : (i - E);
    atomicAdd(&cnt[d], 1);
}

__global__ void bsum_kernel(const int* __restrict__ cnt, int* __restrict__ bsum, int N) {
    __shared__ int sd[256];
    int i = blockIdx.x * 256 + threadIdx.x;
    sd[threadIdx.x] = (i < N) ? cnt[i] : 0;
    __syncthreads();
    for (int off = 128; off; off >>= 1) {
        if (threadIdx.x < off) sd[threadIdx.x] += sd[threadIdx.x + off];
        __syncthreads();
    }
    if (threadIdx.x == 0) bsum[blockIdx.x] = sd[0];
}

__global__ void bscan_kernel(const int* __restrict__ bsum, int* __restrict__ bbase, int NB) {
    __shared__ int sd[256];
    int t = threadIdx.x;
    int v = (t < NB) ? bsum[t] : 0;
    sd[t] = v;
    __syncthreads();
    for (int off = 1; off < 256; off <<= 1) {
        int u = (t >= off) ? sd[t - off] : 0;
        __syncthreads();
        sd[t] += u;
        __syncthreads();
    }
    if (t < NB) bbase[t] = sd[t] - v;
}

__global__ void local_scan_kernel(const int* __restrict__ cnt, const int* __restrict__ bbase,
                                  int* __restrict__ row_ptr, int* __restrict__ cursor,
                                  int N, int ET) {
    __shared__ int sd[256];
    int t = threadIdx.x;
    int i = blockIdx.x * 256 + t;
    int v = (i < N) ? cnt[i] : 0;
    sd[t] = v;
    __syncthreads();
    for (int off = 1; off < 256; off <<= 1) {
        int u = (t >= off) ? sd[t - off] : 0;
        __syncthreads();
        sd[t] += u;
        __syncthreads();
    }
    if (i < N) {
        int e = bbase[blockIdx.x] + sd[t] - v;
        row_ptr[i] = e;
        cursor[i] = e;
    }
    if (i == 0) row_ptr[N] = ET;
}

__global__ void scatter_kernel(const int* __restrict__ ei, int E, int N,
                               int* __restrict__ cursor, int* __restrict__ col) {
    int i = blockIdx.x * blockDim.x + threadIdx.x;
    int tot = E + N;
    if (i >= tot) return;
    int s, d;
    if (i < E) { s = ei[i]; d = ei[E + i]; }
    else       { s = i - E; d = s; }
    int pos = atomicAdd(&cursor[d], 1);
    col[pos] = s;
}

// W1 [256][256] -> W1T bf16 [256][256]  (W1T[c][k] = W1[k][c])
__global__ void cast_w1t_kernel(const float* __restrict__ W1, u16* __restrict__ W1T) {
    int k = blockIdx.x, c = threadIdx.x;
    W1T[c * 256 + k] = f2bf(W1[k * 256 + c]);
}

// ---------------- GEMM1 MFMA (fused fp32->bf16 cast of x in staging) --------------
// block 256 thr = 4 waves (2x2), tile 128x128, BK=64 (4 steps), XOR-swizzled LDS
__global__ __launch_bounds__(256) void gemm1_mfma(const float* __restrict__ Af,
                                                  const u16* __restrict__ Bt,
                                                  const float* __restrict__ att_s,
                                                  const float* __restrict__ att_d,
                                                  u16* __restrict__ h1b,
                                                  float* __restrict__ as1,
                                                  float* __restrict__ ad1,
                                                  int Nnodes) {
    __shared__ __align__(16) u16 As[128 * 64];
    __shared__ __align__(16) u16 Bs[128 * 64];
    int t = threadIdx.x;
    int lane = t & 63, wave = t >> 6;
    int wm = wave >> 1, wn = wave & 1;
    int r0 = blockIdx.x * 128, c0 = blockIdx.y * 128;

    int srow_base = t >> 3;   // + i*32
    int sj = t & 7;

    f32x4 acc[4][4];
#pragma unroll
    for (int m = 0; m < 4; ++m)
#pragma unroll
        for (int n = 0; n < 4; ++n) acc[m][n] = (f32x4){0.f, 0.f, 0.f, 0.f};

    uint4 ra[4], rb[4];
    auto loadA = [&](int row, int k0) -> uint4 {
        int grow = r0 + row;
        if (grow >= Nnodes) return make_uint4(0, 0, 0, 0);
        const float* p = Af + (size_t)grow * 256 + k0 + sj * 8;
        float4 a = *reinterpret_cast<const float4*>(p);
        float4 b = *reinterpret_cast<const float4*>(p + 4);
        uint4 o;
        o.x = (unsigned)f2bf(a.x) | ((unsigned)f2bf(a.y) << 16);
        o.y = (unsigned)f2bf(a.z) | ((unsigned)f2bf(a.w) << 16);
        o.z = (unsigned)f2bf(b.x) | ((unsigned)f2bf(b.y) << 16);
        o.w = (unsigned)f2bf(b.z) | ((unsigned)f2bf(b.w) << 16);
        return o;
    };

#pragma unroll
    for (int i = 0; i < 4; ++i) {
        int row = i * 32 + srow_base;
        ra[i] = loadA(row, 0);
        rb[i] = *reinterpret_cast<const uint4*>(Bt + (size_t)(c0 + row) * 256 + sj * 8);
    }

    char* As8 = (char*)As;
    char* Bs8 = (char*)Bs;

    for (int s = 0; s < 4; ++s) {
        __syncthreads();
#pragma unroll
        for (int i = 0; i < 4; ++i) {
            int row = i * 32 + srow_base;
            int dst = row * 128 + ((sj ^ (row & 7)) << 4);
            *reinterpret_cast<uint4*>(As8 + dst) = ra[i];
            *reinterpret_cast<uint4*>(Bs8 + dst) = rb[i];
        }
        __syncthreads();
        if (s < 3) {
            int k0 = (s + 1) * 64;
#pragma unroll
            for (int i = 0; i < 4; ++i) {
                int row = i * 32 + srow_base;
                ra[i] = loadA(row, k0);
                rb[i] = *reinterpret_cast<const uint4*>(Bt + (size_t)(c0 + row) * 256 + k0 + sj * 8);
            }
        }
#pragma unroll
        for (int ks = 0; ks < 2; ++ks) {
            bf16x8 af[4], bf[4];
            int g = lane >> 4;
            int l15 = lane & 15;
#pragma unroll
            for (int m = 0; m < 4; ++m) {
                int arow = wm * 64 + m * 16 + l15;
                int ajb = (ks * 4 + g) ^ (arow & 7);
                af[m] = *reinterpret_cast<const bf16x8*>(As8 + arow * 128 + ajb * 16);
            }
#pragma unroll
            for (int n = 0; n < 4; ++n) {
                int brow = wn * 64 + n * 16 + l15;
                int bjb = (ks * 4 + g) ^ (brow & 7);
                bf[n] = *reinterpret_cast<const bf16x8*>(Bs8 + brow * 128 + bjb * 16);
            }
#pragma unroll
            for (int m = 0; m < 4; ++m)
#pragma unroll
                for (int n = 0; n < 4; ++n)
                    acc[m][n] = __builtin_amdgcn_mfma_f32_16x16x32_bf16(af[m], bf[n], acc[m][n], 0, 0, 0);
        }
    }

    int l15 = lane & 15;
    int g = lane >> 4;
    int head = blockIdx.y * 2 + wn;
    float asv[4], adv[4];
#pragma unroll
    for (int n = 0; n < 4; ++n) {
        asv[n] = att_s[head * 64 + n * 16 + l15];
        adv[n] = att_d[head * 64 + n * 16 + l15];
    }
#pragma unroll
    for (int m = 0; m < 4; ++m) {
#pragma unroll
        for (int reg = 0; reg < 4; ++reg) {
            int grow = r0 + wm * 64 + m * 16 + g * 4 + reg;
            bool ok = grow < Nnodes;
            float vs = 0.f, vd = 0.f;
#pragma unroll
            for (int n = 0; n < 4; ++n) {
                float v = acc[m][n][reg];
                if (ok) h1b[(size_t)grow * 256 + c0 + wn * 64 + n * 16 + l15] = f2bf(v);
                vs += v * asv[n];
                vd += v * adv[n];
            }
#pragma unroll
            for (int mask = 1; mask < 16; mask <<= 1) {
                vs += __shfl_xor(vs, mask, 64);
                vd += __shfl_xor(vd, mask, 64);
            }
            if (l15 == 0 && ok) {
                as1[grow * 4 + head] = vs;
                ad1[grow * 4 + head] = vd;
            }
        }
    }
}

// ---------------- conv1 softmax stats: alphas (unnormalized) + 1/denom -----------
// one wave per node; 16 lanes per head
__global__ void att_alpha1(const float* __restrict__ as1, const float* __restrict__ ad1,
                           const int* __restrict__ row_ptr, const int* __restrict__ col,
                           float* __restrict__ alphas, float* __restrict__ invl, int N) {
    int idx = blockIdx.x * blockDim.x + threadIdx.x;
    int v = idx >> 6, lane = idx & 63;
    if (v >= N) return;
    int head = lane >> 4, l15 = lane & 15;
    float adst = ad1[v * 4 + head];
    int beg = row_ptr[v], end = row_ptr[v + 1];
    // sweep 1: e -> alphas, track max
    float m = -1e30f;
    for (int p = beg + l15; p < end; p += 16) {
        int u = col[p];
        float e = as1[u * 4 + head] + adst;
        e = e > 0.f ? e : NEG * e;
        alphas[p * 4 + head] = e;
        m = fmaxf(m, e);
    }
#pragma unroll
    for (int mask = 1; mask < 16; mask <<= 1) m = fmaxf(m, __shfl_xor(m, mask, 64));
    // sweep 2: alpha = exp(e-m), sum
    float l = 0.f;
    for (int p = beg + l15; p < end; p += 16) {
        float a = __expf(alphas[p * 4 + head] - m);
        alphas[p * 4 + head] = a;
        l += a;
    }
#pragma unroll
    for (int mask = 1; mask < 16; mask <<= 1) l += __shfl_xor(l, mask, 64);
    if (l15 == 0) invl[v * 4 + head] = 1.f / (l + 1e-16f);
}

// ---------------- conv1 gather: acc = sum alpha * h1[u], normalize at end --------
__global__ void conv1_gather(const u16* __restrict__ h1b, const float* __restrict__ alphas,
                             const float* __restrict__ invl, const int* __restrict__ row_ptr,
                             const int* __restrict__ col, const float* __restrict__ b1,
                             u16* __restrict__ hin2b, int N) {
    int idx = blockIdx.x * blockDim.x + threadIdx.x;
    int v = idx >> 6, lane = idx & 63;
    if (v >= N) return;
    int head = lane >> 4;
    int beg = row_ptr[v], end = row_ptr[v + 1];
    float ax = 0.f, ay = 0.f, az = 0.f, aw = 0.f;
    int p = beg;
    for (; p + 3 < end; p += 4) {
        int u0 = col[p], u1 = col[p + 1], u2 = col[p + 2], u3 = col[p + 3];
        float a0 = alphas[(p + 0) * 4 + head];
        float a1 = alphas[(p + 1) * 4 + head];
        float a2 = alphas[(p + 2) * 4 + head];
        float a3 = alphas[(p + 3) * 4 + head];
        ushort4 h0 = *reinterpret_cast<const ushort4*>(h1b + (size_t)u0 * 256 + lane * 4);
        ushort4 h1 = *reinterpret_cast<const ushort4*>(h1b + (size_t)u1 * 256 + lane * 4);
        ushort4 h2 = *reinterpret_cast<const ushort4*>(h1b + (size_t)u2 * 256 + lane * 4);
        ushort4 h3 = *reinterpret_cast<const ushort4*>(h1b + (size_t)u3 * 256 + lane * 4);
        ax += a0 * bf2f(h0.x) + a1 * bf2f(h1.x) + a2 * bf2f(h2.x) + a3 * bf2f(h3.x);
        ay += a0 * bf2f(h0.y) + a1 * bf2f(h1.y) + a2 * bf2f(h2.y) + a3 * bf2f(h3.y);
        az += a0 * bf2f(h0.z) + a1 * bf2f(h1.z) + a2 * bf2f(h2.z) + a3 * bf2f(h3.z);
        aw += a0 * bf2f(h0.w) + a1 * bf2f(h1.w) + a2 * bf2f(h2.w) + a3 * bf2f(h3.w);
    }
    for (; p < end; ++p) {
        int u = col[p];
        float a = alphas[p * 4 + head];
        ushort4 hv = *reinterpret_cast<const ushort4*>(h1b + (size_t)u * 256 + lane * 4);
        ax += a * bf2f(hv.x);
        ay += a * bf2f(hv.y);
        az += a * bf2f(hv.z);
        aw += a * bf2f(hv.w);
    }
    float inv = invl[v * 4 + head];
    int c = lane * 4;
    ushort4 o;
    o.x = f2bf(fmaxf(ax * inv + b1[c + 0], 0.f));
    o.y = f2bf(fmaxf(ay * inv + b1[c + 1], 0.f));
    o.z = f2bf(fmaxf(az * inv + b1[c + 2], 0.f));
    o.w = f2bf(fmaxf(aw * inv + b1[c + 3], 0.f));
    *reinterpret_cast<ushort4*>(hin2b + (size_t)v * 256 + c) = o;
}

// ---------------- GEMM2 (256->32) fp32 weights (k-major LDS, conflict-free) ------
__global__ __launch_bounds__(256) void gemm2_att(const u16* __restrict__ hin2b,
                                                 const float* __restrict__ W2,
                                                 const float* __restrict__ att_s,
                                                 const float* __restrict__ att_d,
                                                 u16* __restrict__ h2b, float* __restrict__ as2,
                                                 float* __restrict__ ad2, int N) {
    __shared__ __align__(16) float ws2[256 * 32];
    int t = threadIdx.x;
#pragma unroll
    for (int i = 0; i < 8; ++i) {
        int f4 = i * 256 + t;
        *reinterpret_cast<float4*>(ws2 + f4 * 4) = *reinterpret_cast<const float4*>(W2 + f4 * 4);
    }
    __syncthreads();
    int wave = t >> 6, half = (t >> 5) & 1, j = t & 31;
    int nb = blockIdx.x * 32 + wave * 8 + half * 4;
    float acc[4] = {0.f, 0.f, 0.f, 0.f};
    int nmax = N - 1;
    for (int k0 = 0; k0 < 256; k0 += 4) {
        float w0 = ws2[(k0 + 0) * 32 + j];
        float w1 = ws2[(k0 + 1) * 32 + j];
        float w2 = ws2[(k0 + 2) * 32 + j];
        float w3 = ws2[(k0 + 3) * 32 + j];
#pragma unroll
        for (int q = 0; q < 4; ++q) {
            int nc = nb + q; nc = nc > nmax ? nmax : nc;
            ushort4 h = *reinterpret_cast<const ushort4*>(hin2b + (size_t)nc * 256 + k0);
            acc[q] += bf2f(h.x) * w0 + bf2f(h.y) * w1 + bf2f(h.z) * w2 + bf2f(h.w) * w3;
        }
    }
    float asj = att_s[j], adj = att_d[j];
#pragma unroll
    for (int q = 0; q < 4; ++q) {
        int n = nb + q;
        bool ok = n < N;
        float a = acc[q];
        if (ok) h2b[(size_t)n * 32 + j] = f2bf(a);
        float vs = a * asj, vd = a * adj;
#pragma unroll
        for (int mask = 1; mask < 32; mask <<= 1) {
            vs += __shfl_xor(vs, mask, 64);
            vd += __shfl_xor(vd, mask, 64);
        }
        if (j == 0 && ok) { as2[n] = vs; ad2[n] = vd; }
    }
}

// ---------------- conv2 softmax stats ----------------
__global__ void att_alpha2(const float* __restrict__ as2, const float* __restrict__ ad2,
                           const int* __restrict__ row_ptr, const int* __restrict__ col,
                           float* __restrict__ alphas2, float* __restrict__ invl2, int N) {
    int idx = blockIdx.x * blockDim.x + threadIdx.x;
    int v = idx >> 6, lane = idx & 63;
    if (v >= N) return;
    float adst = ad2[v];
    int beg = row_ptr[v], end = row_ptr[v + 1];
    float m = -1e30f;
    for (int p = beg + lane; p < end; p += 64) {
        int u = col[p];
        float e = as2[u] + adst;
        e = e > 0.f ? e : NEG * e;
        alphas2[p] = e;
        m = fmaxf(m, e);
    }
#pragma unroll
    for (int mask = 1; mask < 64; mask <<= 1) m = fmaxf(m, __shfl_xor(m, mask, 64));
    float l = 0.f;
    for (int p = beg + lane; p < end; p += 64) {
        float a = __expf(alphas2[p] - m);
        alphas2[p] = a;
        l += a;
    }
#pragma unroll
    for (int mask = 1; mask < 64; mask <<= 1) l += __shfl_xor(l, mask, 64);
    if (lane == 0) invl2[v] = 1.f / (l + 1e-16f);
}

// ---------------- conv2 gather (32 lanes per node) ----------------
__global__ void conv2_gather(const u16* __restrict__ h2b, const float* __restrict__ alphas2,
                             const float* __restrict__ invl2, const int* __restrict__ row_ptr,
                             const int* __restrict__ col, const float* __restrict__ b2,
                             float* __restrict__ out2, int N) {
    int idx = blockIdx.x * blockDim.x + threadIdx.x;
    int v = idx >> 5, lane = idx & 31;
    if (v >= N) return;
    int beg = row_ptr[v], end = row_ptr[v + 1];
    float acc = 0.f;
    int p = beg;
    for (; p + 3 < end; p += 4) {
        int u0 = col[p], u1 = col[p + 1], u2 = col[p + 2], u3 = col[p + 3];
        float a0 = alphas2[p], a1 = alphas2[p + 1], a2 = alphas2[p + 2], a3 = alphas2[p + 3];
        float v0 = bf2f(h2b[(size_t)u0 * 32 + lane]);
        float v1 = bf2f(h2b[(size_t)u1 * 32 + lane]);
        float v2 = bf2f(h2b[(size_t)u2 * 32 + lane]);
        float v3 = bf2f(h2b[(size_t)u3 * 32 + lane]);
        acc += a0 * v0 + a1 * v1 + a2 * v2 + a3 * v3;
    }
    for (; p < end; ++p) {
        acc += alphas2[p] * bf2f(h2b[(size_t)col[p] * 32 + lane]);
    }
    out2[(size_t)v * 32 + lane] = acc * invl2[v] + b2[lane];
}

// ---------------- pooling + FC head ----------------
__global__ __launch_bounds__(256) void pool_fc(const float* __restrict__ out2,
                                               const int* __restrict__ batch,
                                               const float* __restrict__ fc1w,
                                               const float* __restrict__ fc1b,
                                               const float* __restrict__ fc2w,
                                               const float* __restrict__ fc2b,
                                               float* __restrict__ out, int N) {
    int g = blockIdx.x;
    int lo = 0, hi = N;
    while (lo < hi) { int mid = (lo + hi) >> 1; if (batch[mid] < g) lo = mid + 1; else hi = mid; }
    int s = lo;
    lo = 0; hi = N;
    while (lo < hi) { int mid = (lo + hi) >> 1; if (batch[mid] < g + 1) lo = mid + 1; else hi = mid; }
    int e = lo;

    int c = threadIdx.x & 31, grp = threadIdx.x >> 5;
    float sum = 0.f;
    for (int r = s + grp; r < e; r += 8) sum += out2[(size_t)r * 32 + c];
    __shared__ float part[8][32];
    part[grp][c] = sum;
    __syncthreads();
    __shared__ float g0[32];
    if (grp == 0) {
        float tot = 0.f;
#pragma unroll
        for (int q = 0; q < 8; ++q) tot += part[q][c];
        float cnt = (float)(e - s);
        g0[c] = fmaxf(tot / fmaxf(cnt, 1.0f), 0.f);
    }
    __syncthreads();
    __shared__ float z1[16];
    if (threadIdx.x < 16) {
        float a = fc1b[threadIdx.x];
        for (int k = 0; k < 32; ++k) a += g0[k] * fc1w[k * 16 + threadIdx.x];
        z1[threadIdx.x] = fmaxf(a, 0.f);
    }
    __syncthreads();
    if (threadIdx.x < 16) {
        float a = fc2b[threadIdx.x];
        for (int k = 0; k < 16; ++k) a += z1[k] * fc2w[k * 16 + threadIdx.x];
        out[g * 16 + threadIdx.x] = fmaxf(a, 0.f);
    }
}

// ---------------- host launcher ----------------
extern "C" void kernel_launch(void* const* d_in, const int* in_sizes, int n_in,
                              void* d_out, int out_size, void* d_ws, size_t ws_size,
                              hipStream_t stream) {
    const float* x      = (const float*)d_in[0];
    const int*   ei     = (const int*)d_in[1];
    const int*   batch  = (const int*)d_in[2];
    const float* W1     = (const float*)d_in[3];
    const float* att_s1 = (const float*)d_in[4];
    const float* att_d1 = (const float*)d_in[5];
    const float* b1     = (const float*)d_in[6];
    const float* W2     = (const float*)d_in[7];
    const float* att_s2 = (const float*)d_in[8];
    const float* att_d2 = (const float*)d_in[9];
    const float* b2     = (const float*)d_in[10];
    const float* fc1w   = (const float*)d_in[11];
    const float* fc1b   = (const float*)d_in[12];
    const float* fc2w   = (const float*)d_in[13];
    const float* fc2b   = (const float*)d_in[14];
    float* out = (float*)d_out;

    int N = in_sizes[0] / 256;      // 50000
    int E = in_sizes[1] / 2;        // 800000
    int ET = E + N;
    int Mpad = ((N + 127) / 128) * 128;
    int NB = (N + 255) / 256;

    char* ws = (char*)d_ws;
    size_t off = 0;
    auto alloc = [&](size_t bytes) { size_t o = off; off = (off + bytes + 255) & ~255ULL; return o; };
    u16*  w1t    = (u16*)(ws + alloc(256 * 256 * 2));
    u16*  h1b    = (u16*)(ws + alloc((size_t)N * 256 * 2));
    float* as1   = (float*)(ws + alloc((size_t)N * 4 * 4));
    float* ad1   = (float*)(ws + alloc((size_t)N * 4 * 4));
    u16*  hin2b  = (u16*)(ws + alloc((size_t)N * 256 * 2));
    u16*  h2b    = (u16*)(ws + alloc((size_t)N * 32 * 2));
    float* as2   = (float*)(ws + alloc((size_t)N * 4));
    float* ad2   = (float*)(ws + alloc((size_t)N * 4));
    float* out2  = (float*)(ws + alloc((size_t)N * 32 * 4));
    int* cnt     = (int*)(ws + alloc((size_t)(N + 1) * 4));
    int* row_ptr = (int*)(ws + alloc((size_t)(N + 1) * 4));
    int* cursor  = (int*)(ws + alloc((size_t)(N + 1) * 4));
    int* col     = (int*)(ws + alloc((size_t)ET * 4));
    int* bsum    = (int*)(ws + alloc((size_t)NB * 4));
    int* bbase   = (int*)(ws + alloc((size_t)NB * 4));
    float* alphas1 = (float*)(ws + alloc((size_t)ET * 4 * 4));
    float* invl1   = (float*)(ws + alloc((size_t)N * 4 * 4));
    float* alphas2 = (float*)(ws + alloc((size_t)ET * 4));
    float* invl2   = (float*)(ws + alloc((size_t)N * 4));
    (void)ws_size; (void)n_in; (void)out_size;

    // weight cast (independent of CSR)
    cast_w1t_kernel<<<256, 256, 0, stream>>>(W1, w1t);

    // CSR build
    zero_i32<<<(N + 1 + 255) / 256, 256, 0, stream>>>(cnt, N + 1);
    hist_kernel<<<(ET + 255) / 256, 256, 0, stream>>>(ei, E, N, cnt);
    bsum_kernel<<<NB, 256, 0, stream>>>(cnt, bsum, N);
    bscan_kernel<<<1, 256, 0, stream>>>(bsum, bbase, NB);
    local_scan_kernel<<<NB, 256, 0, stream>>>(cnt, bbase, row_ptr, cursor, N, ET);
    scatter_kernel<<<(ET + 255) / 256, 256, 0, stream>>>(ei, E, N, cursor, col);

    // conv1
    dim3 g1(Mpad / 128, 2);
    gemm1_mfma<<<g1, 256, 0, stream>>>(x, w1t, att_s1, att_d1, h1b, as1, ad1, N);
    att_alpha1<<<(N * 64 + 255) / 256, 256, 0, stream>>>(as1, ad1, row_ptr, col, alphas1, invl1, N);
    conv1_gather<<<(N * 64 + 255) / 256, 256, 0, stream>>>(h1b, alphas1, invl1, row_ptr, col, b1, hin2b, N);

    // conv2
    gemm2_att<<<(N + 31) / 32, 256, 0, stream>>>(hin2b, W2, att_s2, att_d2, h2b, as2, ad2, N);
    att_alpha2<<<(N * 64 + 255) / 256, 256, 0, stream>>>(as2, ad2, row_ptr, col, alphas2, invl2, N);
    conv2_gather<<<(N * 32 + 255) / 256, 256, 0, stream>>>(h2b, alphas2, invl2, row_ptr, col, b2, out2, N);

    // pool + fc
    pool_fc<<<64, 256, 0, stream>>>(out2, batch, fc1w, fc1b, fc2w, fc2b, out, N);
}